// Round 13
// baseline (302.098 us; speedup 1.0000x reference)
//
#include <hip/hip_runtime.h>
#include <hip/hip_bf16.h>

// ---------- helpers ----------
typedef __attribute__((ext_vector_type(8))) short bf16x8;
typedef __attribute__((ext_vector_type(4))) float f32x4;
typedef __attribute__((ext_vector_type(4))) float f4v;
typedef __attribute__((ext_vector_type(4))) unsigned short us4;
typedef __attribute__((ext_vector_type(8))) unsigned short us8;

__device__ __forceinline__ unsigned short bf16_rne(float f) {
  unsigned u = __float_as_uint(f);
  unsigned r = u + 0x7fffu + ((u >> 16) & 1u);
  return (unsigned short)(r >> 16);
}

__device__ __forceinline__ void gload16(const void* g, void* l) {
  typedef const __attribute__((address_space(1))) unsigned int* gas;
  typedef __attribute__((address_space(3))) unsigned int* las;
  __builtin_amdgcn_global_load_lds((gas)g, (las)l, 16, 0, 0);
}

__device__ __forceinline__ float lane_f(float v, int l) {
  return __int_as_float(__builtin_amdgcn_readlane(__float_as_int(v), l));
}

template <int CTRL>
__device__ __forceinline__ float dpp_add(float x) {
  return x + __int_as_float(__builtin_amdgcn_update_dpp(0, __float_as_int(x), CTRL, 0xf, 0xf, true));
}

#define BAR() asm volatile("s_barrier" ::: "memory")
#define VMCNT0() asm volatile("s_waitcnt vmcnt(0)" ::: "memory")
#define LGKM4() asm volatile("s_waitcnt lgkmcnt(4)" ::: "memory")
#define LGKM0() asm volatile("s_waitcnt lgkmcnt(0)" ::: "memory")
#define SB() __builtin_amdgcn_sched_barrier(0)

// ---------- transpose+cast W [R][C] f32 -> WT [C][R] bf16 ----------
__global__ __launch_bounds__(256) void transcast(const float* __restrict__ src,
                                                 unsigned short* __restrict__ dst,
                                                 int R, int C) {
  __shared__ float t[32][33];
  const int tx = threadIdx.x & 31, ty = threadIdx.x >> 5;
  const int c0 = blockIdx.x * 32, r0 = blockIdx.y * 32;
#pragma unroll
  for (int j = 0; j < 4; j++)
    t[ty + j * 8][tx] = src[(size_t)(r0 + ty + j * 8) * C + c0 + tx];
  __syncthreads();
#pragma unroll
  for (int j = 0; j < 4; j++)
    dst[(size_t)(c0 + ty + j * 8) * R + r0 + tx] = bf16_rne(t[tx][ty + j * 8]);
}

// ---------- shared MFMA quarter ----------
#define MFMA_Q(AO, BO, MOFF, NOFF)                                                  \
  __builtin_amdgcn_s_setprio(1);                                                    \
  _Pragma("unroll") for (int i_ = 0; i_ < 4; ++i_)                                  \
  _Pragma("unroll") for (int j_ = 0; j_ < 2; ++j_)                                  \
  _Pragma("unroll") for (int ks_ = 0; ks_ < 2; ++ks_)                               \
    acc[(MOFF) + i_][(NOFF) + j_] = __builtin_amdgcn_mfma_f32_16x16x32_bf16(        \
        AO[i_][ks_], BO[j_][ks_], acc[(MOFF) + i_][(NOFF) + j_], 0, 0, 0);          \
  __builtin_amdgcn_s_setprio(0);

#define RDA(KS, ACH, MH, I) \
  (*(const bf16x8*)(lsc + ((ACH) * 32768 + (MH) * 8192 + (I) * 2048) + ((KS) ? vA_1 : vA_0)))
#define RDB(KS, BCH, JI) \
  (*(const bf16x8*)(lsc + ((BCH) * 32768 + (JI) * 2048) + ((KS) ? vB_1 : vB_0)))

// stage one full B tile (256 rows x 64k) -> chunk CHOFF (4 x gload16/lane)
#define STGB(CHOFF, T)                                                            \
  {                                                                               \
    const char* Bp_ = BgL + (size_t)(T) * 128;                                    \
    gload16(Bp_,                (char*)ls + (CHOFF) + wid * 1024);                \
    gload16(Bp_ + 64 * ld,      (char*)ls + (CHOFF) + 8192 + wid * 1024);         \
    gload16(Bp_ + 128 * ld,     (char*)ls + (CHOFF) + 16384 + wid * 1024);        \
    gload16(Bp_ + 192 * ld,     (char*)ls + (CHOFF) + 24576 + wid * 1024);        \
  }

// ---------- GEMM1 fused X-cast: H = relu(X_f32 * W1T^T + b1), 256x256, BK=64 ----------
// A: f32 loaded to regs (pre-swizzled source, T14 issue-early/write-late), cast
// to bf16 in-reg, ds_write_b128 into the SAME linear LDS bytes gload16 used.
// B: global_load_lds as before. Read-side layout/swizzle identical to R5/R12.
#define LOADA(T)                                                                  \
  {                                                                               \
    const char* p_ = AgF + (size_t)(T) * 256;                                     \
    _Pragma("unroll") for (int r = 0; r < 4; ++r) {                               \
      const char* q_ = p_ + (size_t)((r >> 1) * 128 + (r & 1) * 64) * 4096;       \
      rg[2 * r]     = *(const f4v*)q_;                                            \
      rg[2 * r + 1] = *(const f4v*)(q_ + 16);                                     \
    }                                                                             \
  }

#define CVTWR(ASO)                                                                \
  {                                                                               \
    _Pragma("unroll") for (int r = 0; r < 4; ++r) {                               \
      us8 v_;                                                                     \
      _Pragma("unroll") for (int e = 0; e < 4; ++e) {                             \
        v_[e]     = bf16_rne(rg[2 * r][e]);                                       \
        v_[4 + e] = bf16_rne(rg[2 * r + 1][e]);                                   \
      }                                                                           \
      *(us8*)((char*)ls + (ASO) + (r >> 1) * 16384 + (r & 1) * 8192 +             \
              wid * 1024 + lane * 16) = v_;                                       \
    }                                                                             \
  }

#define TILE_F(ACH, BCH, ASO, BSO, T)                                             \
  {                                                                               \
    BAR();                                                                        \
    _Pragma("unroll") for (int i = 0; i < 4; ++i) {                               \
      afr[i][0] = RDA(0, ACH, 0, i); afr[i][1] = RDA(1, ACH, 0, i);               \
    }                                                                             \
    _Pragma("unroll") for (int j = 0; j < 2; ++j) {                               \
      bfr0[j][0] = RDB(0, BCH, j); bfr0[j][1] = RDB(1, BCH, j);                   \
    }                                                                             \
    _Pragma("unroll") for (int j = 0; j < 2; ++j) {                               \
      bfr1[j][0] = RDB(0, BCH, 2 + j); bfr1[j][1] = RDB(1, BCH, 2 + j);           \
    }                                                                             \
    STGB(BSO, T);                                                                 \
    LOADA(T);                                                                     \
    LGKM4(); SB();                                                                \
    MFMA_Q(afr, bfr0, 0, 0);                                                      \
    LGKM0(); SB();                                                                \
    MFMA_Q(afr, bfr1, 0, 2);                                                      \
    _Pragma("unroll") for (int i = 0; i < 4; ++i) {                               \
      afr[i][0] = RDA(0, ACH, 1, i); afr[i][1] = RDA(1, ACH, 1, i);               \
    }                                                                             \
    LGKM0(); SB();                                                                \
    MFMA_Q(afr, bfr1, 4, 2);                                                      \
    MFMA_Q(afr, bfr0, 4, 0);                                                      \
    VMCNT0(); SB();                                                               \
    CVTWR(ASO);                                                                   \
    LGKM0();                                                                      \
  }

__global__ __launch_bounds__(512) void gemm1f(const float* __restrict__ sup,
                                              const float* __restrict__ qry,
                                              const unsigned short* __restrict__ W1T,
                                              const float* __restrict__ bias,
                                              unsigned short* __restrict__ H) {
  __shared__ __attribute__((aligned(16))) short ls[4][16384];  // A0,A1,B0,B1
  const int tid = threadIdx.x, lane = tid & 63, wid = tid >> 6;
  const int wm = wid >> 2, wn = wid & 3;
  const int l15 = lane & 15, lg = lane >> 4;

  // bijective XCD swizzle (nwg = 768, %8 == 0)
  int lin = blockIdx.y * gridDim.x + blockIdx.x;
  int nwg = gridDim.x * gridDim.y;
  int swz = (lin & 7) * (nwg >> 3) + (lin >> 3);
  int bx = swz % gridDim.x, by = swz / gridDim.x;
  const int m0 = by * 256, n0 = bx * 256;

  constexpr int K = 1024;
  const size_t ld = (size_t)K * 2;      // W1T row bytes
  const char* Bg = (const char*)W1T + (size_t)n0 * ld;
  constexpr int NT = K >> 6;            // 16
  const char* lsc = (const char*)ls;

  const int swz4 = (l15 & 7) << 4;
  const int bk0 = (l15 * 128 + lg * 16) ^ swz4;
  const int bk1 = (l15 * 128 + 64 + lg * 16) ^ swz4;
  const int vA_0 = bk0 + wm * 16384, vA_1 = bk1 + wm * 16384;
  const int vB_0 = bk0 + wn * 8192 + 65536, vB_1 = bk1 + wn * 8192 + 65536;

  const int srow = wid * 8 + (lane >> 3);
  const int kperm = ((lane & 7) ^ (lane >> 3)) << 4;
  const char* BgL = Bg + (size_t)srow * ld + kperm;

  // A f32 source (X = concat(sup[8192 rows], qry[16384 rows]), row = 4096 B)
  const char* Asrc = (m0 < 8192) ? (const char*)sup + (size_t)m0 * 4096
                                 : (const char*)qry + (size_t)(m0 - 8192) * 4096;
  const char* AgF = Asrc + (size_t)srow * 4096 + (size_t)kperm * 2;

  f32x4 acc[8][4] = {};
  bf16x8 afr[4][2], bfr0[2][2], bfr1[2][2];
  f4v rg[8];

  // prologue: tile 0 -> A0 (reg-cast path), B0 (gload_lds)
  STGB(65536, 0);
  LOADA(0);
  VMCNT0();
  CVTWR(0);
  LGKM0();

  for (int u = 0; u < NT; u += 2) {
    int t1 = u + 1;
    int t2 = u + 2; if (t2 >= NT) t2 = 0;  // wrap: harmless redundant prefetch
    TILE_F(0, 0, 32768, 98304, t1);        // read A0,B0; stage t1 -> A1,B1
    TILE_F(1, 1, 0, 65536, t2);            // read A1,B1; stage t2 -> A0,B0
  }

  float bv[4];
#pragma unroll
  for (int nf = 0; nf < 4; ++nf) bv[nf] = bias[n0 + wn * 64 + nf * 16 + l15];
#pragma unroll
  for (int mf = 0; mf < 8; ++mf) {
    int rbase = m0 + wm * 128 + mf * 16 + lg * 4;
#pragma unroll
    for (int nf = 0; nf < 4; ++nf) {
      int col = n0 + wn * 64 + nf * 16 + l15;
#pragma unroll
      for (int j = 0; j < 4; ++j) {
        float v = acc[mf][nf][j] + bv[nf];
        v = v > 0.f ? v : 0.f;
        H[(size_t)(rbase + j) * 2048 + col] = bf16_rne(v);
      }
    }
  }
}

// ---------- GEMM2: 192x256 tile -> grid (2,128) = 256 blocks = 1/CU (R12 verbatim) ----------
#define MFMA_T(AO, BO, MOFF, NOFF)                                                  \
  __builtin_amdgcn_s_setprio(1);                                                    \
  _Pragma("unroll") for (int i_ = 0; i_ < 3; ++i_)                                  \
  _Pragma("unroll") for (int j_ = 0; j_ < 2; ++j_)                                  \
  _Pragma("unroll") for (int ks_ = 0; ks_ < 2; ++ks_)                               \
    acc[(MOFF) + i_][(NOFF) + j_] = __builtin_amdgcn_mfma_f32_16x16x32_bf16(        \
        AO[i_][ks_], BO[j_][ks_], acc[(MOFF) + i_][(NOFF) + j_], 0, 0, 0);          \
  __builtin_amdgcn_s_setprio(0);

#define RA2(KS, ACH, MH, I) \
  (*(const bf16x8*)(lsc + ((ACH) * 24576 + (MH) * 6144 + (I) * 2048) + ((KS) ? vA_1 : vA_0)))
#define RB2(KS, BCH, JI) \
  (*(const bf16x8*)(lsc + ((BCH) * 32768 + (JI) * 2048) + ((KS) ? vB_1 : vB_0)))

#define STGA2(CHOFF, T)                                                           \
  {                                                                               \
    const char* p_ = AgL + (size_t)(T) * 128;                                     \
    gload16(p_,               (char*)ls + (CHOFF) + wid * 3072);                  \
    gload16(p_ + 8 * ld,      (char*)ls + (CHOFF) + wid * 3072 + 1024);           \
    gload16(p_ + 16 * ld,     (char*)ls + (CHOFF) + wid * 3072 + 2048);           \
  }
#define STGB2(CHOFF, T)                                                           \
  {                                                                               \
    const char* p_ = BgL + (size_t)(T) * 128;                                     \
    gload16(p_,               (char*)ls + (CHOFF) + wid * 4096);                  \
    gload16(p_ + 8 * ld,      (char*)ls + (CHOFF) + wid * 4096 + 1024);           \
    gload16(p_ + 16 * ld,     (char*)ls + (CHOFF) + wid * 4096 + 2048);           \
    gload16(p_ + 24 * ld,     (char*)ls + (CHOFF) + wid * 4096 + 3072);           \
  }

#define TILE2(ACH, BCH, ASO, BSO, T)                                              \
  {                                                                               \
    VMCNT0();                                                                     \
    BAR();                                                                        \
    _Pragma("unroll") for (int i = 0; i < 3; ++i) {                               \
      afl[i][0] = RA2(0, ACH, 0, i); afl[i][1] = RA2(1, ACH, 0, i);               \
    }                                                                             \
    _Pragma("unroll") for (int j = 0; j < 2; ++j) {                               \
      bfr0[j][0] = RB2(0, BCH, j); bfr0[j][1] = RB2(1, BCH, j);                   \
    }                                                                             \
    _Pragma("unroll") for (int j = 0; j < 2; ++j) {                               \
      bfr1[j][0] = RB2(0, BCH, 2 + j); bfr1[j][1] = RB2(1, BCH, 2 + j);           \
    }                                                                             \
    STGA2(ASO, T); STGB2(BSO, T);                                                 \
    LGKM4(); SB();                                                                \
    MFMA_T(afl, bfr0, 0, 0);                                                      \
    LGKM0(); SB();                                                                \
    MFMA_T(afl, bfr1, 0, 2);                                                      \
    _Pragma("unroll") for (int i = 0; i < 3; ++i) {                               \
      afl[i][0] = RA2(0, ACH, 1, i); afl[i][1] = RA2(1, ACH, 1, i);               \
    }                                                                             \
    LGKM0(); SB();                                                                \
    MFMA_T(afl, bfr1, 3, 2);                                                      \
    MFMA_T(afl, bfr0, 3, 0);                                                      \
  }

__global__ __launch_bounds__(512) void gemm192(const unsigned short* __restrict__ A,
                                               const unsigned short* __restrict__ BT,
                                               const float* __restrict__ bias,
                                               float* __restrict__ Cout) {
  __shared__ __attribute__((aligned(16))) short ls[57344];  // 112 KiB
  const int tid = threadIdx.x, lane = tid & 63, wid = tid >> 6;
  const int wm = wid >> 2, wn = wid & 3;
  const int l15 = lane & 15, lg = lane >> 4;

  int lin = blockIdx.y * gridDim.x + blockIdx.x;
  int nwg = gridDim.x * gridDim.y;
  int swz = (lin & 7) * (nwg >> 3) + (lin >> 3);
  int bx = swz % gridDim.x, by = swz / gridDim.x;
  const int m0 = by * 192, n0 = bx * 256;

  constexpr int K = 2048;
  const size_t ld = (size_t)K * 2;
  const char* Ag = (const char*)A + (size_t)m0 * ld;
  const char* Bg = (const char*)BT + (size_t)n0 * ld;
  constexpr int NT = K >> 6;  // 32
  const char* lsc = (const char*)ls;

  const int swz4 = (l15 & 7) << 4;
  const int bk0 = (l15 * 128 + lg * 16) ^ swz4;
  const int bk1 = (l15 * 128 + 64 + lg * 16) ^ swz4;
  const int vA_0 = bk0 + wm * 12288, vA_1 = bk1 + wm * 12288;
  const int vB_0 = bk0 + wn * 8192 + 49152, vB_1 = bk1 + wn * 8192 + 49152;

  const int kperm = ((lane & 7) ^ (lane >> 3)) << 4;
  const char* AgL = Ag + (size_t)(wid * 24 + (lane >> 3)) * ld + kperm;
  const char* BgL = Bg + (size_t)(wid * 32 + (lane >> 3)) * ld + kperm;

  f32x4 acc[6][4] = {};
  bf16x8 afl[3][2], bfr0[2][2], bfr1[2][2];

  STGA2(0, 0);
  STGB2(49152, 0);

  for (int u = 0; u < NT; u += 2) {
    int t1 = u + 1;
    int t2 = u + 2; if (t2 >= NT) t2 = 0;
    TILE2(0, 0, 24576, 81920, t1);
    TILE2(1, 1, 0, 49152, t2);
  }

  float bv[4];
#pragma unroll
  for (int nf = 0; nf < 4; ++nf) bv[nf] = bias[n0 + wn * 64 + nf * 16 + l15];
#pragma unroll
  for (int mf = 0; mf < 6; ++mf) {
    int rbase = m0 + wm * 96 + mf * 16 + lg * 4;
#pragma unroll
    for (int nf = 0; nf < 4; ++nf) {
      int col = n0 + wn * 64 + nf * 16 + l15;
#pragma unroll
      for (int j = 0; j < 4; ++j)
        Cout[(size_t)(rbase + j) * 512 + col] = acc[mf][nf][j] + bv[nf];
    }
  }
}

// ---------- per-task K = Es Es^T + eps*I, eta2 = log2(e)/(2*max row abs-sum) ----------
__global__ __launch_bounds__(256) void makeK(const float* __restrict__ E,
                                             float* __restrict__ Km,
                                             float* __restrict__ eta2v) {
  __shared__ float es[32][512];  // 64 KB
  const int b = blockIdx.x, tid = threadIdx.x;
  const float4* Eb = (const float4*)(E + (size_t)b * 32 * 512);
  float4* es4 = (float4*)&es[0][0];
  for (int i = tid; i < 32 * 128; i += 256) es4[i] = Eb[i];
  __syncthreads();

  const int s = tid >> 3, tq = tid & 7;
  const float4* rs4 = (const float4*)&es[s][0];
  const float4* rt0 = (const float4*)&es[tq * 4 + 0][0];
  const float4* rt1 = (const float4*)&es[tq * 4 + 1][0];
  const float4* rt2 = (const float4*)&es[tq * 4 + 2][0];
  const float4* rt3 = (const float4*)&es[tq * 4 + 3][0];
  float4 a0 = {0, 0, 0, 0}, a1 = {0, 0, 0, 0}, a2 = {0, 0, 0, 0}, a3 = {0, 0, 0, 0};
  for (int dd = 0; dd < 128; ++dd) {
    float4 av = rs4[dd];
    float4 b0 = rt0[dd], b1 = rt1[dd], b2 = rt2[dd], b3 = rt3[dd];
    a0.x = fmaf(av.x, b0.x, a0.x); a0.y = fmaf(av.y, b0.y, a0.y);
    a0.z = fmaf(av.z, b0.z, a0.z); a0.w = fmaf(av.w, b0.w, a0.w);
    a1.x = fmaf(av.x, b1.x, a1.x); a1.y = fmaf(av.y, b1.y, a1.y);
    a1.z = fmaf(av.z, b1.z, a1.z); a1.w = fmaf(av.w, b1.w, a1.w);
    a2.x = fmaf(av.x, b2.x, a2.x); a2.y = fmaf(av.y, b2.y, a2.y);
    a2.z = fmaf(av.z, b2.z, a2.z); a2.w = fmaf(av.w, b2.w, a2.w);
    a3.x = fmaf(av.x, b3.x, a3.x); a3.y = fmaf(av.y, b3.y, a3.y);
    a3.z = fmaf(av.z, b3.z, a3.z); a3.w = fmaf(av.w, b3.w, a3.w);
  }
  float kv[4] = { (a0.x + a0.y) + (a0.z + a0.w), (a1.x + a1.y) + (a1.z + a1.w),
                  (a2.x + a2.y) + (a2.z + a2.w), (a3.x + a3.y) + (a3.z + a3.w) };
  float p = 0.f;
#pragma unroll
  for (int j = 0; j < 4; j++) {
    if (s == tq * 4 + j) kv[j] += 1e-6f;
    p += fabsf(kv[j]);
    Km[(size_t)b * 1024 + s * 32 + tq * 4 + j] = kv[j];
  }
  p += __shfl_xor(p, 1); p += __shfl_xor(p, 2); p += __shfl_xor(p, 4);
  __syncthreads();
  float* rs = &es[0][0];
  if (tq == 0) rs[s] = p;
  __syncthreads();
  if (tid < 32) {
    float m = rs[tid];
    m = fmaxf(m, __shfl_xor(m, 1));
    m = fmaxf(m, __shfl_xor(m, 2));
    m = fmaxf(m, __shfl_xor(m, 4));
    m = fmaxf(m, __shfl_xor(m, 8));
    m = fmaxf(m, __shfl_xor(m, 16));
    if (tid == 0) eta2v[b] = 1.4426950408889634f / (2.0f * m);
  }
}

// ---------- QP: 500 EG iterations, one wave per task (R8: readlane + full DPP) ----------
__global__ __launch_bounds__(256) void qp_kernel(const float* __restrict__ Km,
                                                 const float* __restrict__ eta2v,
                                                 float* __restrict__ alp) {
  const int lane = threadIdx.x & 63, wid = threadIdx.x >> 6;
  const int b = blockIdx.x * 4 + wid;
  const int s = lane & 31;
  const float* Kb = Km + (size_t)b * 1024;
  float kr[32];
#pragma unroll
  for (int i = 0; i < 8; i++) {
    float4 v = ((const float4*)(Kb + s * 32))[i];
    kr[i * 4 + 0] = v.x; kr[i * 4 + 1] = v.y; kr[i * 4 + 2] = v.z; kr[i * 4 + 3] = v.w;
  }
  const float kd = Kb[s * 33];
  const float eta2 = eta2v[b];
  const float c2p = fmaf(eta2, kd, 1.0f);
  const float m4n = -4.0f * eta2;
  float w = 0.03125f;
  for (int it = 0; it < 500; ++it) {
    float c0 = 0.f, c1 = 0.f, c2 = 0.f, c3 = 0.f, c4 = 0.f, c5 = 0.f, c6 = 0.f, c7 = 0.f;
#pragma unroll
    for (int t = 0; t < 4; ++t) {
      c0 = fmaf(kr[t],      lane_f(w, t),      c0);
      c1 = fmaf(kr[4 + t],  lane_f(w, 4 + t),  c1);
      c2 = fmaf(kr[8 + t],  lane_f(w, 8 + t),  c2);
      c3 = fmaf(kr[12 + t], lane_f(w, 12 + t), c3);
      c4 = fmaf(kr[16 + t], lane_f(w, 16 + t), c4);
      c5 = fmaf(kr[20 + t], lane_f(w, 20 + t), c5);
      c6 = fmaf(kr[24 + t], lane_f(w, 24 + t), c6);
      c7 = fmaf(kr[28 + t], lane_f(w, 28 + t), c7);
    }
    float tK = (((c0 + c1) + (c2 + c3)) + ((c4 + c5) + (c6 + c7)));
    float r = w;
    r = dpp_add<0x128>(r);
    r = dpp_add<0x124>(r);
    r = dpp_add<0x122>(r);
    r = dpp_add<0x121>(r);
    r = dpp_add<0x142>(r);
    r = dpp_add<0x143>(r);
    float R2 = __builtin_amdgcn_rcpf(lane_f(r, 63));
    float z = fmaf(m4n * R2, tK, c2p);
    w = (w * R2) * __builtin_amdgcn_exp2f(z);
  }
  float r = w;
  r = dpp_add<0x128>(r);
  r = dpp_add<0x124>(r);
  r = dpp_add<0x122>(r);
  r = dpp_add<0x121>(r);
  r = dpp_add<0x142>(r);
  r = dpp_add<0x143>(r);
  float R2 = __builtin_amdgcn_rcpf(lane_f(r, 63));
  if (lane < 32) alp[(size_t)b * 32 + s] = 2.0f * w * R2;
}

// ---------- centers[b] = sum_s alpha[b][s] * Es[b][s][:] ----------
__global__ __launch_bounds__(128) void centers_k(const float* __restrict__ alp,
                                                 const float* __restrict__ E,
                                                 float* __restrict__ ctr) {
  const int b = blockIdx.x, t = threadIdx.x;
  __shared__ float av[32];
  if (t < 32) av[t] = alp[(size_t)b * 32 + t];
  __syncthreads();
  const float4* Eb = (const float4*)(E + (size_t)b * 32 * 512);
  float4 c = {0, 0, 0, 0};
#pragma unroll 8
  for (int sIdx = 0; sIdx < 32; sIdx++) {
    float a = av[sIdx];
    float4 v = Eb[sIdx * 128 + t];
    c.x = fmaf(a, v.x, c.x); c.y = fmaf(a, v.y, c.y);
    c.z = fmaf(a, v.z, c.z); c.w = fmaf(a, v.w, c.w);
  }
  ((float4*)ctr)[b * 128 + t] = c;
}

// ---------- logits[b][q] = -||center[b] - Eq[b][q]||^2 ----------
__global__ __launch_bounds__(256) void logits_k(const float* __restrict__ ctr,
                                                const float* __restrict__ E,
                                                float* __restrict__ out) {
  const int b = blockIdx.x, lane = threadIdx.x & 63, w = threadIdx.x >> 6;
  const float4* C4 = (const float4*)(ctr + (size_t)b * 512);
  const float4 cA = C4[lane * 2], cB = C4[lane * 2 + 1];
  const float4* Q4 = (const float4*)(E + (size_t)(8192 + b * 64) * 512);
  for (int q = w; q < 64; q += 4) {
    float4 e0 = Q4[(size_t)q * 128 + lane * 2];
    float4 e1 = Q4[(size_t)q * 128 + lane * 2 + 1];
    float d, ss = 0.f;
    d = cA.x - e0.x; ss = fmaf(d, d, ss);
    d = cA.y - e0.y; ss = fmaf(d, d, ss);
    d = cA.z - e0.z; ss = fmaf(d, d, ss);
    d = cA.w - e0.w; ss = fmaf(d, d, ss);
    d = cB.x - e1.x; ss = fmaf(d, d, ss);
    d = cB.y - e1.y; ss = fmaf(d, d, ss);
    d = cB.z - e1.z; ss = fmaf(d, d, ss);
    d = cB.w - e1.w; ss = fmaf(d, d, ss);
    ss += __shfl_xor(ss, 1);  ss += __shfl_xor(ss, 2);  ss += __shfl_xor(ss, 4);
    ss += __shfl_xor(ss, 8);  ss += __shfl_xor(ss, 16); ss += __shfl_xor(ss, 32);
    if (lane == 0) out[b * 64 + q] = -ss;
  }
}

// ---------- launch ----------
extern "C" void kernel_launch(void* const* d_in, const int* in_sizes, int n_in,
                              void* d_out, int out_size, void* d_ws, size_t ws_size,
                              hipStream_t stream) {
  const float* sup = (const float*)d_in[0];
  const float* qry = (const float*)d_in[1];
  const float* W1  = (const float*)d_in[2];
  const float* b1  = (const float*)d_in[3];
  const float* W2  = (const float*)d_in[4];
  const float* b2  = (const float*)d_in[5];
  float* out = (float*)d_out;

  char* ws = (char*)d_ws;
  unsigned short* H   = (unsigned short*)(ws);               // 24576*2048*2
  float* E    = (float*)(ws + 100663296);                    // 24576*512*4
  unsigned short* W1T = (unsigned short*)(ws + 150994944);
  unsigned short* W2T = (unsigned short*)(ws + 155189248);
  float* Km   = (float*)(ws + 157286400);
  float* eta2 = (float*)(ws + 158334976);
  float* alp  = (float*)(ws + 158336000);
  float* ctr  = (float*)(ws + 158368768);

  transcast<<<dim3(64, 32), dim3(256), 0, stream>>>(W1, W1T, 1024, 2048);
  transcast<<<dim3(16, 64), dim3(256), 0, stream>>>(W2, W2T, 2048, 512);
  gemm1f<<<dim3(8, 96), dim3(512), 0, stream>>>(sup, qry, W1T, b1, H);
  gemm192<<<dim3(2, 128), dim3(512), 0, stream>>>(H, W2T, b2, E);
  makeK<<<dim3(256), dim3(256), 0, stream>>>(E, Km, eta2);
  qp_kernel<<<dim3(64), dim3(256), 0, stream>>>(Km, eta2, alp);
  centers_k<<<dim3(256), dim3(128), 0, stream>>>(alp, E, ctr);
  logits_k<<<dim3(256), dim3(256), 0, stream>>>(ctr, E, out);
}

// Round 14
// 301.875 us; speedup vs baseline: 1.0007x; 1.0007x over previous
//
#include <hip/hip_runtime.h>
#include <hip/hip_bf16.h>

// ---------- helpers ----------
typedef __attribute__((ext_vector_type(8))) short bf16x8;
typedef __attribute__((ext_vector_type(4))) float f32x4;
typedef __attribute__((ext_vector_type(4))) unsigned short us4;

__device__ __forceinline__ unsigned short bf16_rne(float f) {
  unsigned u = __float_as_uint(f);
  unsigned r = u + 0x7fffu + ((u >> 16) & 1u);
  return (unsigned short)(r >> 16);
}

__device__ __forceinline__ void gload16(const void* g, void* l) {
  typedef const __attribute__((address_space(1))) unsigned int* gas;
  typedef __attribute__((address_space(3))) unsigned int* las;
  __builtin_amdgcn_global_load_lds((gas)g, (las)l, 16, 0, 0);
}

__device__ __forceinline__ float lane_f(float v, int l) {
  return __int_as_float(__builtin_amdgcn_readlane(__float_as_int(v), l));
}

template <int CTRL>
__device__ __forceinline__ float dpp_add(float x) {
  return x + __int_as_float(__builtin_amdgcn_update_dpp(0, __float_as_int(x), CTRL, 0xf, 0xf, true));
}

#define BAR() asm volatile("s_barrier" ::: "memory")
#define VMCNT0() asm volatile("s_waitcnt vmcnt(0)" ::: "memory")
#define VMCNT4() asm volatile("s_waitcnt vmcnt(4)" ::: "memory")
#define LGKM8() asm volatile("s_waitcnt lgkmcnt(8)" ::: "memory")
#define LGKM4() asm volatile("s_waitcnt lgkmcnt(4)" ::: "memory")
#define LGKM0() asm volatile("s_waitcnt lgkmcnt(0)" ::: "memory")
#define SB() __builtin_amdgcn_sched_barrier(0)

// ---------- cast inputs (support+query) f32 -> bf16, flat [24576][1024] ----------
__global__ __launch_bounds__(256) void castx(const float* __restrict__ sup,
                                             const float* __restrict__ qry,
                                             unsigned short* __restrict__ X) {
  const int stride = gridDim.x * blockDim.x;
  for (int i = blockIdx.x * blockDim.x + threadIdx.x; i < 6291456; i += stride) {
    float4 v = (i < 2097152) ? ((const float4*)sup)[i] : ((const float4*)qry)[i - 2097152];
    us4 o = { bf16_rne(v.x), bf16_rne(v.y), bf16_rne(v.z), bf16_rne(v.w) };
    *(us4*)(X + (size_t)i * 4) = o;
  }
}

// ---------- transpose+cast W [R][C] f32 -> WT [C][R] bf16 ----------
__global__ __launch_bounds__(256) void transcast(const float* __restrict__ src,
                                                 unsigned short* __restrict__ dst,
                                                 int R, int C) {
  __shared__ float t[32][33];
  const int tx = threadIdx.x & 31, ty = threadIdx.x >> 5;
  const int c0 = blockIdx.x * 32, r0 = blockIdx.y * 32;
#pragma unroll
  for (int j = 0; j < 4; j++)
    t[ty + j * 8][tx] = src[(size_t)(r0 + ty + j * 8) * C + c0 + tx];
  __syncthreads();
#pragma unroll
  for (int j = 0; j < 4; j++)
    dst[(size_t)(c0 + ty + j * 8) * R + r0 + tx] = bf16_rne(t[tx][ty + j * 8]);
}

// ---------- shared MFMA quarter (16 MFMA) ----------
#define MFMA_Q(AO, BO, MOFF, NOFF)                                                  \
  __builtin_amdgcn_s_setprio(1);                                                    \
  _Pragma("unroll") for (int i_ = 0; i_ < 4; ++i_)                                  \
  _Pragma("unroll") for (int j_ = 0; j_ < 2; ++j_)                                  \
  _Pragma("unroll") for (int ks_ = 0; ks_ < 2; ++ks_)                               \
    acc[(MOFF) + i_][(NOFF) + j_] = __builtin_amdgcn_mfma_f32_16x16x32_bf16(        \
        AO[i_][ks_], BO[j_][ks_], acc[(MOFF) + i_][(NOFF) + j_], 0, 0, 0);          \
  __builtin_amdgcn_s_setprio(0);

// ---------- GEMM1: faithful m201 8-phase, 256x256, BK=64, counted vmcnt(4) ----------
// 8 chunks of 16KB: A0h0@0 A0h1@16K A1h0@32K A1h1@48K B0h0@64K B0h1@80K B1h0@96K B1h1@112K.
// Per 2-tile iter: 8 phases {reads || 1 half-tile stage -> bar -> lgkm0+SB ->
// setprio 16xMFMA -> bar}. vmcnt(4) ONLY at P3/P7, one phase BEFORE the
// dependent reads: the following barrier publishes per-wave vmcnt retirement
// to all waves (vmcnt is per-wave; gate must precede a barrier, not the reads).
#define RD_A8(BUF, QM)                                                              \
  _Pragma("unroll") for (int i = 0; i < 4; ++i) {                                   \
    afr[i][0] = *(const bf16x8*)(lsc + (BUF) * 32768 + ((QM) * 4 + i) * 2048 + vA_0); \
    afr[i][1] = *(const bf16x8*)(lsc + (BUF) * 32768 + ((QM) * 4 + i) * 2048 + vA_1); \
  }
#define RD_B4(BUF, QN, DST)                                                         \
  _Pragma("unroll") for (int j = 0; j < 2; ++j) {                                   \
    DST[j][0] = *(const bf16x8*)(lsc + (BUF) * 32768 + ((QN) * 2 + j) * 2048 + vB_0); \
    DST[j][1] = *(const bf16x8*)(lsc + (BUF) * 32768 + ((QN) * 2 + j) * 2048 + vB_1); \
  }
// stage one 16KB half-chunk (2 gloads/lane): rows H*128+[0,128) of tile T
#define STGH(CHOFF, GPTR, H, T)                                                     \
  gload16((GPTR) + (size_t)((H) * 128) * ld + (size_t)(T) * 128,                    \
          (char*)ls + (CHOFF) + wid * 1024);                                        \
  gload16((GPTR) + (size_t)((H) * 128 + 64) * ld + (size_t)(T) * 128,               \
          (char*)ls + (CHOFF) + 8192 + wid * 1024);

__global__ __launch_bounds__(512) void gemm1_8p(const unsigned short* __restrict__ A,
                                                const unsigned short* __restrict__ BT,
                                                const float* __restrict__ bias,
                                                unsigned short* __restrict__ H) {
  __shared__ __attribute__((aligned(16))) short ls[65536];  // 128 KiB
  const int tid = threadIdx.x, lane = tid & 63, wid = tid >> 6;
  const int wm = wid >> 2, wn = wid & 3;
  const int l15 = lane & 15, lg = lane >> 4;

  // bijective XCD swizzle (nwg = 768, %8 == 0)
  int lin = blockIdx.y * gridDim.x + blockIdx.x;
  int nwg = gridDim.x * gridDim.y;
  int swz = (lin & 7) * (nwg >> 3) + (lin >> 3);
  int bx = swz % gridDim.x, by = swz / gridDim.x;
  const int m0 = by * 256, n0 = bx * 256;

  constexpr int K = 1024;
  const size_t ld = (size_t)K * 2;
  const char* Ag = (const char*)A + (size_t)m0 * ld;
  const char* Bg = (const char*)BT + (size_t)n0 * ld;
  const char* lsc = (const char*)ls;

  // per-lane invariant read bases (full 3-bit swizzle; ks inside XOR)
  const int swz4 = (l15 & 7) << 4;
  const int bk0 = (l15 * 128 + lg * 16) ^ swz4;
  const int bk1 = (l15 * 128 + 64 + lg * 16) ^ swz4;
  const int vA_0 = bk0 + wm * 16384, vA_1 = bk1 + wm * 16384;
  const int vB_0 = bk0 + (wn >> 1) * 16384 + (wn & 1) * 8192 + 65536;
  const int vB_1 = bk1 + (wn >> 1) * 16384 + (wn & 1) * 8192 + 65536;

  // staging source (pre-swizzled column, rule #21)
  const int srow = wid * 8 + (lane >> 3);
  const int kperm = ((lane & 7) ^ (lane >> 3)) << 4;
  const char* AgL = Ag + (size_t)srow * ld + kperm;
  const char* BgL = Bg + (size_t)srow * ld + kperm;

  f32x4 acc[8][4] = {};
  bf16x8 afr[4][2], bfr0[2][2], bfr1[2][2];

  // prologue: A0,B0 <- tile0 (oldest 8 loads), B1 <- tile1 (newest 4)
  STGH(0, AgL, 0, 0);      STGH(16384, AgL, 1, 0);
  STGH(65536, BgL, 0, 0);  STGH(81920, BgL, 1, 0);
  STGH(98304, BgL, 0, 1);  STGH(114688, BgL, 1, 1);
  VMCNT4();   // retire A0,B0 (own); barrier publishes cross-wave
  BAR();

  for (int it = 0; it < 8; ++it) {
    const int t1 = 2 * it + 1;
    int t2a = 2 * it + 2; if (t2a >= 16) t2a = 0;   // wrap: redundant prefetch
    int t2b = 2 * it + 3; if (t2b >= 16) t2b -= 16;
    // P0: buf0 q(0,0); stage A1h0 <- t1
    RD_A8(0, 0); RD_B4(0, 0, bfr0);
    STGH(32768, AgL, 0, t1);
    LGKM8();
    BAR(); LGKM0(); SB();
    MFMA_Q(afr, bfr0, 0, 0);
    BAR();
    // P1: q(0,1); stage A1h1 <- t1
    RD_B4(0, 1, bfr1);
    STGH(49152, AgL, 1, t1);
    BAR(); LGKM0(); SB();
    MFMA_Q(afr, bfr1, 0, 2);
    BAR();
    // P2: q(1,1); stage B0h0 <- t2a
    RD_A8(0, 1);
    STGH(65536, BgL, 0, t2a);
    BAR(); LGKM0(); SB();
    MFMA_Q(afr, bfr1, 4, 2);
    BAR();
    // P3: q(1,0); stage B0h1 <- t2a; GATE for P4's reads (A1: P0/P1, B1: prev P6/P7)
    STGH(81920, BgL, 1, t2a);
    VMCNT4();
    BAR(); SB();
    MFMA_Q(afr, bfr0, 4, 0);
    BAR();
    // P4: buf1 q(0,0); stage A0h0 <- t2a
    RD_A8(1, 0); RD_B4(1, 0, bfr0);
    STGH(0, AgL, 0, t2a);
    LGKM8();
    BAR(); LGKM0(); SB();
    MFMA_Q(afr, bfr0, 0, 0);
    BAR();
    // P5: q(0,1); stage A0h1 <- t2a
    RD_B4(1, 1, bfr1);
    STGH(16384, AgL, 1, t2a);
    BAR(); LGKM0(); SB();
    MFMA_Q(afr, bfr1, 0, 2);
    BAR();
    // P6: q(1,1); stage B1h0 <- t2b
    RD_A8(1, 1);
    STGH(98304, BgL, 0, t2b);
    BAR(); LGKM0(); SB();
    MFMA_Q(afr, bfr1, 4, 2);
    BAR();
    // P7: q(1,0); stage B1h1 <- t2b; GATE for next P0 (A0: P4/P5, B0: P2/P3)
    STGH(114688, BgL, 1, t2b);
    VMCNT4();
    BAR(); SB();
    MFMA_Q(afr, bfr0, 4, 0);
    BAR();
  }

  float bv[4];
#pragma unroll
  for (int nf = 0; nf < 4; ++nf) bv[nf] = bias[n0 + wn * 64 + nf * 16 + l15];
#pragma unroll
  for (int mf = 0; mf < 8; ++mf) {
    int rbase = m0 + wm * 128 + mf * 16 + lg * 4;
#pragma unroll
    for (int nf = 0; nf < 4; ++nf) {
      int col = n0 + wn * 64 + nf * 16 + l15;
#pragma unroll
      for (int j = 0; j < 4; ++j) {
        float v = acc[mf][nf][j] + bv[nf];
        v = v > 0.f ? v : 0.f;
        H[(size_t)(rbase + j) * 2048 + col] = bf16_rne(v);
      }
    }
  }
}

// ---------- GEMM2: 192x256 tile -> 256 blocks = 1/CU (R12 verbatim) ----------
#define MFMA_T(AO, BO, MOFF, NOFF)                                                  \
  __builtin_amdgcn_s_setprio(1);                                                    \
  _Pragma("unroll") for (int i_ = 0; i_ < 3; ++i_)                                  \
  _Pragma("unroll") for (int j_ = 0; j_ < 2; ++j_)                                  \
  _Pragma("unroll") for (int ks_ = 0; ks_ < 2; ++ks_)                               \
    acc[(MOFF) + i_][(NOFF) + j_] = __builtin_amdgcn_mfma_f32_16x16x32_bf16(        \
        AO[i_][ks_], BO[j_][ks_], acc[(MOFF) + i_][(NOFF) + j_], 0, 0, 0);          \
  __builtin_amdgcn_s_setprio(0);

#define RA2(KS, ACH, MH, I) \
  (*(const bf16x8*)(lsc + ((ACH) * 24576 + (MH) * 6144 + (I) * 2048) + ((KS) ? vA_1 : vA_0)))
#define RB2(KS, BCH, JI) \
  (*(const bf16x8*)(lsc + ((BCH) * 32768 + (JI) * 2048) + ((KS) ? vB_1 : vB_0)))

#define STGA2(CHOFF, T)                                                           \
  {                                                                               \
    const char* p_ = AgL + (size_t)(T) * 128;                                     \
    gload16(p_,               (char*)ls + (CHOFF) + wid * 3072);                  \
    gload16(p_ + 8 * ld,      (char*)ls + (CHOFF) + wid * 3072 + 1024);           \
    gload16(p_ + 16 * ld,     (char*)ls + (CHOFF) + wid * 3072 + 2048);           \
  }
#define STGB2(CHOFF, T)                                                           \
  {                                                                               \
    const char* p_ = BgL + (size_t)(T) * 128;                                     \
    gload16(p_,               (char*)ls + (CHOFF) + wid * 4096);                  \
    gload16(p_ + 8 * ld,      (char*)ls + (CHOFF) + wid * 4096 + 1024);           \
    gload16(p_ + 16 * ld,     (char*)ls + (CHOFF) + wid * 4096 + 2048);           \
    gload16(p_ + 24 * ld,     (char*)ls + (CHOFF) + wid * 4096 + 3072);           \
  }

#define TILE2(ACH, BCH, ASO, BSO, T)                                              \
  {                                                                               \
    VMCNT0();                                                                     \
    BAR();                                                                        \
    _Pragma("unroll") for (int i = 0; i < 3; ++i) {                               \
      afl[i][0] = RA2(0, ACH, 0, i); afl[i][1] = RA2(1, ACH, 0, i);               \
    }                                                                             \
    _Pragma("unroll") for (int j = 0; j < 2; ++j) {                               \
      bfr0[j][0] = RB2(0, BCH, j); bfr0[j][1] = RB2(1, BCH, j);                   \
    }                                                                             \
    _Pragma("unroll") for (int j = 0; j < 2; ++j) {                               \
      bfr1[j][0] = RB2(0, BCH, 2 + j); bfr1[j][1] = RB2(1, BCH, 2 + j);           \
    }                                                                             \
    STGA2(ASO, T); STGB2(BSO, T);                                                 \
    LGKM4(); SB();                                                                \
    MFMA_T(afl, bfr0, 0, 0);                                                      \
    LGKM0(); SB();                                                                \
    MFMA_T(afl, bfr1, 0, 2);                                                      \
    _Pragma("unroll") for (int i = 0; i < 3; ++i) {                               \
      afl[i][0] = RA2(0, ACH, 1, i); afl[i][1] = RA2(1, ACH, 1, i);               \
    }                                                                             \
    LGKM0(); SB();                                                                \
    MFMA_T(afl, bfr1, 3, 2);                                                      \
    MFMA_T(afl, bfr0, 3, 0);                                                      \
  }

__global__ __launch_bounds__(512) void gemm192(const unsigned short* __restrict__ A,
                                               const unsigned short* __restrict__ BT,
                                               const float* __restrict__ bias,
                                               float* __restrict__ Cout) {
  __shared__ __attribute__((aligned(16))) short ls[57344];  // 112 KiB
  const int tid = threadIdx.x, lane = tid & 63, wid = tid >> 6;
  const int wm = wid >> 2, wn = wid & 3;
  const int l15 = lane & 15, lg = lane >> 4;

  int lin = blockIdx.y * gridDim.x + blockIdx.x;
  int nwg = gridDim.x * gridDim.y;
  int swz = (lin & 7) * (nwg >> 3) + (lin >> 3);
  int bx = swz % gridDim.x, by = swz / gridDim.x;
  const int m0 = by * 192, n0 = bx * 256;

  constexpr int K = 2048;
  const size_t ld = (size_t)K * 2;
  const char* Ag = (const char*)A + (size_t)m0 * ld;
  const char* Bg = (const char*)BT + (size_t)n0 * ld;
  constexpr int NT = K >> 6;  // 32
  const char* lsc = (const char*)ls;

  const int swz4 = (l15 & 7) << 4;
  const int bk0 = (l15 * 128 + lg * 16) ^ swz4;
  const int bk1 = (l15 * 128 + 64 + lg * 16) ^ swz4;
  const int vA_0 = bk0 + wm * 12288, vA_1 = bk1 + wm * 12288;
  const int vB_0 = bk0 + wn * 8192 + 49152, vB_1 = bk1 + wn * 8192 + 49152;

  const int kperm = ((lane & 7) ^ (lane >> 3)) << 4;
  const char* AgL = Ag + (size_t)(wid * 24 + (lane >> 3)) * ld + kperm;
  const char* BgL = Bg + (size_t)(wid * 32 + (lane >> 3)) * ld + kperm;

  f32x4 acc[6][4] = {};
  bf16x8 afl[3][2], bfr0[2][2], bfr1[2][2];

  STGA2(0, 0);
  STGB2(49152, 0);

  for (int u = 0; u < NT; u += 2) {
    int t1 = u + 1;
    int t2 = u + 2; if (t2 >= NT) t2 = 0;
    TILE2(0, 0, 24576, 81920, t1);
    TILE2(1, 1, 0, 49152, t2);
  }

  float bv[4];
#pragma unroll
  for (int nf = 0; nf < 4; ++nf) bv[nf] = bias[n0 + wn * 64 + nf * 16 + l15];
#pragma unroll
  for (int mf = 0; mf < 6; ++mf) {
    int rbase = m0 + wm * 96 + mf * 16 + lg * 4;
#pragma unroll
    for (int nf = 0; nf < 4; ++nf) {
      int col = n0 + wn * 64 + nf * 16 + l15;
#pragma unroll
      for (int j = 0; j < 4; ++j)
        Cout[(size_t)(rbase + j) * 512 + col] = acc[mf][nf][j] + bv[nf];
    }
  }
}

// ---------- per-task K = Es Es^T + eps*I, eta2 = log2(e)/(2*max row abs-sum) ----------
__global__ __launch_bounds__(256) void makeK(const float* __restrict__ E,
                                             float* __restrict__ Km,
                                             float* __restrict__ eta2v) {
  __shared__ float es[32][512];  // 64 KB
  const int b = blockIdx.x, tid = threadIdx.x;
  const float4* Eb = (const float4*)(E + (size_t)b * 32 * 512);
  float4* es4 = (float4*)&es[0][0];
  for (int i = tid; i < 32 * 128; i += 256) es4[i] = Eb[i];
  __syncthreads();

  const int s = tid >> 3, tq = tid & 7;
  const float4* rs4 = (const float4*)&es[s][0];
  const float4* rt0 = (const float4*)&es[tq * 4 + 0][0];
  const float4* rt1 = (const float4*)&es[tq * 4 + 1][0];
  const float4* rt2 = (const float4*)&es[tq * 4 + 2][0];
  const float4* rt3 = (const float4*)&es[tq * 4 + 3][0];
  float4 a0 = {0, 0, 0, 0}, a1 = {0, 0, 0, 0}, a2 = {0, 0, 0, 0}, a3 = {0, 0, 0, 0};
  for (int dd = 0; dd < 128; ++dd) {
    float4 av = rs4[dd];
    float4 b0 = rt0[dd], b1 = rt1[dd], b2 = rt2[dd], b3 = rt3[dd];
    a0.x = fmaf(av.x, b0.x, a0.x); a0.y = fmaf(av.y, b0.y, a0.y);
    a0.z = fmaf(av.z, b0.z, a0.z); a0.w = fmaf(av.w, b0.w, a0.w);
    a1.x = fmaf(av.x, b1.x, a1.x); a1.y = fmaf(av.y, b1.y, a1.y);
    a1.z = fmaf(av.z, b1.z, a1.z); a1.w = fmaf(av.w, b1.w, a1.w);
    a2.x = fmaf(av.x, b2.x, a2.x); a2.y = fmaf(av.y, b2.y, a2.y);
    a2.z = fmaf(av.z, b2.z, a2.z); a2.w = fmaf(av.w, b2.w, a2.w);
    a3.x = fmaf(av.x, b3.x, a3.x); a3.y = fmaf(av.y, b3.y, a3.y);
    a3.z = fmaf(av.z, b3.z, a3.z); a3.w = fmaf(av.w, b3.w, a3.w);
  }
  float kv[4] = { (a0.x + a0.y) + (a0.z + a0.w), (a1.x + a1.y) + (a1.z + a1.w),
                  (a2.x + a2.y) + (a2.z + a2.w), (a3.x + a3.y) + (a3.z + a3.w) };
  float p = 0.f;
#pragma unroll
  for (int j = 0; j < 4; j++) {
    if (s == tq * 4 + j) kv[j] += 1e-6f;
    p += fabsf(kv[j]);
    Km[(size_t)b * 1024 + s * 32 + tq * 4 + j] = kv[j];
  }
  p += __shfl_xor(p, 1); p += __shfl_xor(p, 2); p += __shfl_xor(p, 4);
  __syncthreads();
  float* rs = &es[0][0];
  if (tq == 0) rs[s] = p;
  __syncthreads();
  if (tid < 32) {
    float m = rs[tid];
    m = fmaxf(m, __shfl_xor(m, 1));
    m = fmaxf(m, __shfl_xor(m, 2));
    m = fmaxf(m, __shfl_xor(m, 4));
    m = fmaxf(m, __shfl_xor(m, 8));
    m = fmaxf(m, __shfl_xor(m, 16));
    if (tid == 0) eta2v[b] = 1.4426950408889634f / (2.0f * m);
  }
}

// ---------- QP: 500 EG iterations, one wave per task (readlane + full DPP) ----------
__global__ __launch_bounds__(256) void qp_kernel(const float* __restrict__ Km,
                                                 const float* __restrict__ eta2v,
                                                 float* __restrict__ alp) {
  const int lane = threadIdx.x & 63, wid = threadIdx.x >> 6;
  const int b = blockIdx.x * 4 + wid;
  const int s = lane & 31;
  const float* Kb = Km + (size_t)b * 1024;
  float kr[32];
#pragma unroll
  for (int i = 0; i < 8; i++) {
    float4 v = ((const float4*)(Kb + s * 32))[i];
    kr[i * 4 + 0] = v.x; kr[i * 4 + 1] = v.y; kr[i * 4 + 2] = v.z; kr[i * 4 + 3] = v.w;
  }
  const float kd = Kb[s * 33];
  const float eta2 = eta2v[b];
  const float c2p = fmaf(eta2, kd, 1.0f);
  const float m4n = -4.0f * eta2;
  float w = 0.03125f;
  for (int it = 0; it < 500; ++it) {
    float c0 = 0.f, c1 = 0.f, c2 = 0.f, c3 = 0.f, c4 = 0.f, c5 = 0.f, c6 = 0.f, c7 = 0.f;
#pragma unroll
    for (int t = 0; t < 4; ++t) {
      c0 = fmaf(kr[t],      lane_f(w, t),      c0);
      c1 = fmaf(kr[4 + t],  lane_f(w, 4 + t),  c1);
      c2 = fmaf(kr[8 + t],  lane_f(w, 8 + t),  c2);
      c3 = fmaf(kr[12 + t], lane_f(w, 12 + t), c3);
      c4 = fmaf(kr[16 + t], lane_f(w, 16 + t), c4);
      c5 = fmaf(kr[20 + t], lane_f(w, 20 + t), c5);
      c6 = fmaf(kr[24 + t], lane_f(w, 24 + t), c6);
      c7 = fmaf(kr[28 + t], lane_f(w, 28 + t), c7);
    }
    float tK = (((c0 + c1) + (c2 + c3)) + ((c4 + c5) + (c6 + c7)));
    float r = w;
    r = dpp_add<0x128>(r);
    r = dpp_add<0x124>(r);
    r = dpp_add<0x122>(r);
    r = dpp_add<0x121>(r);
    r = dpp_add<0x142>(r);
    r = dpp_add<0x143>(r);
    float R2 = __builtin_amdgcn_rcpf(lane_f(r, 63));
    float z = fmaf(m4n * R2, tK, c2p);
    w = (w * R2) * __builtin_amdgcn_exp2f(z);
  }
  float r = w;
  r = dpp_add<0x128>(r);
  r = dpp_add<0x124>(r);
  r = dpp_add<0x122>(r);
  r = dpp_add<0x121>(r);
  r = dpp_add<0x142>(r);
  r = dpp_add<0x143>(r);
  float R2 = __builtin_amdgcn_rcpf(lane_f(r, 63));
  if (lane < 32) alp[(size_t)b * 32 + s] = 2.0f * w * R2;
}

// ---------- centers[b] = sum_s alpha[b][s] * Es[b][s][:] ----------
__global__ __launch_bounds__(128) void centers_k(const float* __restrict__ alp,
                                                 const float* __restrict__ E,
                                                 float* __restrict__ ctr) {
  const int b = blockIdx.x, t = threadIdx.x;
  __shared__ float av[32];
  if (t < 32) av[t] = alp[(size_t)b * 32 + t];
  __syncthreads();
  const float4* Eb = (const float4*)(E + (size_t)b * 32 * 512);
  float4 c = {0, 0, 0, 0};
#pragma unroll 8
  for (int sIdx = 0; sIdx < 32; sIdx++) {
    float a = av[sIdx];
    float4 v = Eb[sIdx * 128 + t];
    c.x = fmaf(a, v.x, c.x); c.y = fmaf(a, v.y, c.y);
    c.z = fmaf(a, v.z, c.z); c.w = fmaf(a, v.w, c.w);
  }
  ((float4*)ctr)[b * 128 + t] = c;
}

// ---------- logits[b][q] = -||center[b] - Eq[b][q]||^2 ----------
__global__ __launch_bounds__(256) void logits_k(const float* __restrict__ ctr,
                                                const float* __restrict__ E,
                                                float* __restrict__ out) {
  const int b = blockIdx.x, lane = threadIdx.x & 63, w = threadIdx.x >> 6;
  const float4* C4 = (const float4*)(ctr + (size_t)b * 512);
  const float4 cA = C4[lane * 2], cB = C4[lane * 2 + 1];
  const float4* Q4 = (const float4*)(E + (size_t)(8192 + b * 64) * 512);
  for (int q = w; q < 64; q += 4) {
    float4 e0 = Q4[(size_t)q * 128 + lane * 2];
    float4 e1 = Q4[(size_t)q * 128 + lane * 2 + 1];
    float d, ss = 0.f;
    d = cA.x - e0.x; ss = fmaf(d, d, ss);
    d = cA.y - e0.y; ss = fmaf(d, d, ss);
    d = cA.z - e0.z; ss = fmaf(d, d, ss);
    d = cA.w - e0.w; ss = fmaf(d, d, ss);
    d = cB.x - e1.x; ss = fmaf(d, d, ss);
    d = cB.y - e1.y; ss = fmaf(d, d, ss);
    d = cB.z - e1.z; ss = fmaf(d, d, ss);
    d = cB.w - e1.w; ss = fmaf(d, d, ss);
    ss += __shfl_xor(ss, 1);  ss += __shfl_xor(ss, 2);  ss += __shfl_xor(ss, 4);
    ss += __shfl_xor(ss, 8);  ss += __shfl_xor(ss, 16); ss += __shfl_xor(ss, 32);
    if (lane == 0) out[b * 64 + q] = -ss;
  }
}

// ---------- launch ----------
extern "C" void kernel_launch(void* const* d_in, const int* in_sizes, int n_in,
                              void* d_out, int out_size, void* d_ws, size_t ws_size,
                              hipStream_t stream) {
  const float* sup = (const float*)d_in[0];
  const float* qry = (const float*)d_in[1];
  const float* W1  = (const float*)d_in[2];
  const float* b1  = (const float*)d_in[3];
  const float* W2  = (const float*)d_in[4];
  const float* b2  = (const float*)d_in[5];
  float* out = (float*)d_out;

  char* ws = (char*)d_ws;
  unsigned short* H   = (unsigned short*)(ws);               // 24576*2048*2
  unsigned short* Xbf = (unsigned short*)(ws + 100663296);   // 24576*1024*2
  float* E    = (float*)(ws + 100663296);                    // aliases Xbf (dead after GEMM1)
  unsigned short* W1T = (unsigned short*)(ws + 150994944);
  unsigned short* W2T = (unsigned short*)(ws + 155189248);
  float* Km   = (float*)(ws + 157286400);
  float* eta2 = (float*)(ws + 158334976);
  float* alp  = (float*)(ws + 158336000);
  float* ctr  = (float*)(ws + 158368768);

  castx<<<dim3(2048), dim3(256), 0, stream>>>(sup, qry, Xbf);
  transcast<<<dim3(64, 32), dim3(256), 0, stream>>>(W1, W1T, 1024, 2048);
  transcast<<<dim3(16, 64), dim3(256), 0, stream>>>(W2, W2T, 2048, 512);
  gemm1_8p<<<dim3(8, 96), dim3(512), 0, stream>>>(Xbf, W1T, b1, H);
  gemm192<<<dim3(2, 128), dim3(512), 0, stream>>>(H, W2T, b2, E);
  makeK<<<dim3(256), dim3(256), 0, stream>>>(E, Km, eta2);
  qp_kernel<<<dim3(64), dim3(256), 0, stream>>>(Km, eta2, alp);
  centers_k<<<dim3(256), dim3(128), 0, stream>>>(alp, E, ctr);
  logits_k<<<dim3(256), dim3(256), 0, stream>>>(ctr, E, out);
}

// Round 15
// 298.391 us; speedup vs baseline: 1.0124x; 1.0117x over previous
//
#include <hip/hip_runtime.h>
#include <hip/hip_bf16.h>

// ---------- helpers ----------
typedef __attribute__((ext_vector_type(8))) short bf16x8;
typedef __attribute__((ext_vector_type(4))) float f32x4;
typedef __attribute__((ext_vector_type(4))) unsigned short us4;

__device__ __forceinline__ unsigned short bf16_rne(float f) {
  unsigned u = __float_as_uint(f);
  unsigned r = u + 0x7fffu + ((u >> 16) & 1u);
  return (unsigned short)(r >> 16);
}

__device__ __forceinline__ void gload16(const void* g, void* l) {
  typedef const __attribute__((address_space(1))) unsigned int* gas;
  typedef __attribute__((address_space(3))) unsigned int* las;
  __builtin_amdgcn_global_load_lds((gas)g, (las)l, 16, 0, 0);
}

__device__ __forceinline__ float lane_f(float v, int l) {
  return __int_as_float(__builtin_amdgcn_readlane(__float_as_int(v), l));
}

template <int CTRL>
__device__ __forceinline__ float dpp_add(float x) {
  return x + __int_as_float(__builtin_amdgcn_update_dpp(0, __float_as_int(x), CTRL, 0xf, 0xf, true));
}

#define BAR() asm volatile("s_barrier" ::: "memory")
#define VMCNT0() asm volatile("s_waitcnt vmcnt(0)" ::: "memory")
#define LGKM4() asm volatile("s_waitcnt lgkmcnt(4)" ::: "memory")
#define LGKM0() asm volatile("s_waitcnt lgkmcnt(0)" ::: "memory")
#define SB() __builtin_amdgcn_sched_barrier(0)

// ---------- cast inputs (support+query) f32 -> bf16, flat [24576][1024] ----------
__global__ __launch_bounds__(256) void castx(const float* __restrict__ sup,
                                             const float* __restrict__ qry,
                                             unsigned short* __restrict__ X) {
  const int stride = gridDim.x * blockDim.x;
  for (int i = blockIdx.x * blockDim.x + threadIdx.x; i < 6291456; i += stride) {
    float4 v = (i < 2097152) ? ((const float4*)sup)[i] : ((const float4*)qry)[i - 2097152];
    us4 o = { bf16_rne(v.x), bf16_rne(v.y), bf16_rne(v.z), bf16_rne(v.w) };
    *(us4*)(X + (size_t)i * 4) = o;
  }
}

// ---------- transpose+cast W [R][C] f32 -> WT [C][R] bf16 ----------
__global__ __launch_bounds__(256) void transcast(const float* __restrict__ src,
                                                 unsigned short* __restrict__ dst,
                                                 int R, int C) {
  __shared__ float t[32][33];
  const int tx = threadIdx.x & 31, ty = threadIdx.x >> 5;
  const int c0 = blockIdx.x * 32, r0 = blockIdx.y * 32;
#pragma unroll
  for (int j = 0; j < 4; j++)
    t[ty + j * 8][tx] = src[(size_t)(r0 + ty + j * 8) * C + c0 + tx];
  __syncthreads();
#pragma unroll
  for (int j = 0; j < 4; j++)
    dst[(size_t)(c0 + ty + j * 8) * R + r0 + tx] = bf16_rne(t[tx][ty + j * 8]);
}

// ---------- 256x256 bf16 GEMM (R5 structure: 1 barrier/K-tile) ----------
#define MFMA_Q(AO, BO, MOFF, NOFF)                                                  \
  __builtin_amdgcn_s_setprio(1);                                                    \
  _Pragma("unroll") for (int i_ = 0; i_ < 4; ++i_)                                  \
  _Pragma("unroll") for (int j_ = 0; j_ < 2; ++j_)                                  \
  _Pragma("unroll") for (int ks_ = 0; ks_ < 2; ++ks_)                               \
    acc[(MOFF) + i_][(NOFF) + j_] = __builtin_amdgcn_mfma_f32_16x16x32_bf16(        \
        AO[i_][ks_], BO[j_][ks_], acc[(MOFF) + i_][(NOFF) + j_], 0, 0, 0);          \
  __builtin_amdgcn_s_setprio(0);

#define RDA(KS, ACH, MH, I) \
  (*(const bf16x8*)(lsc + ((ACH) * 32768 + (MH) * 8192 + (I) * 2048) + ((KS) ? vA_1 : vA_0)))
#define RDB(KS, BCH, JI) \
  (*(const bf16x8*)(lsc + ((BCH) * 32768 + (JI) * 2048) + ((KS) ? vB_1 : vB_0)))

#define STG(GLP, CHOFF, HALF)                                                     \
  gload16((GLP) + (size_t)((HALF) * 128) * ld,                                    \
          (char*)ls + ((CHOFF) + (HALF) * 16384) + wid * 1024);                   \
  gload16((GLP) + (size_t)((HALF) * 128 + 64) * ld,                               \
          (char*)ls + ((CHOFF) + (HALF) * 16384 + 8192) + wid * 1024);

#define TILE(ACH, BCH, ASO, BSO, T)                                               \
  {                                                                               \
    VMCNT0();                                                                     \
    BAR();                                                                        \
    _Pragma("unroll") for (int i = 0; i < 4; ++i) {                               \
      afr[i][0] = RDA(0, ACH, 0, i); afr[i][1] = RDA(1, ACH, 0, i);               \
    }                                                                             \
    _Pragma("unroll") for (int j = 0; j < 2; ++j) {                               \
      bfr0[j][0] = RDB(0, BCH, j); bfr0[j][1] = RDB(1, BCH, j);                   \
    }                                                                             \
    _Pragma("unroll") for (int j = 0; j < 2; ++j) {                               \
      bfr1[j][0] = RDB(0, BCH, 2 + j); bfr1[j][1] = RDB(1, BCH, 2 + j);           \
    }                                                                             \
    const char* Ap_ = AgL + (size_t)(T) * 128;                                    \
    const char* Bp_ = BgL + (size_t)(T) * 128;                                    \
    STG(Ap_, ASO, 0); STG(Ap_, ASO, 1);                                           \
    STG(Bp_, BSO, 0); STG(Bp_, BSO, 1);                                           \
    LGKM4(); SB();                                                                \
    MFMA_Q(afr, bfr0, 0, 0);                                                      \
    LGKM0(); SB();                                                                \
    MFMA_Q(afr, bfr1, 0, 2);                                                      \
    _Pragma("unroll") for (int i = 0; i < 4; ++i) {                               \
      afr[i][0] = RDA(0, ACH, 1, i); afr[i][1] = RDA(1, ACH, 1, i);               \
    }                                                                             \
    LGKM0(); SB();                                                                \
    MFMA_Q(afr, bfr1, 4, 2);                                                      \
    MFMA_Q(afr, bfr0, 4, 0);                                                      \
  }

template <int ACT, int OUTBF>
__global__ __launch_bounds__(512) void gemm256(const unsigned short* __restrict__ A,
                                               const unsigned short* __restrict__ BT,
                                               const float* __restrict__ bias,
                                               void* __restrict__ Cout,
                                               int M, int N, int K) {
  __shared__ __attribute__((aligned(16))) short ls[4][16384];  // A0,A1,B0,B1
  const int tid = threadIdx.x, lane = tid & 63, wid = tid >> 6;
  const int wm = wid >> 2, wn = wid & 3;
  const int l15 = lane & 15, lg = lane >> 4;

  int lin = blockIdx.y * gridDim.x + blockIdx.x;
  int nwg = gridDim.x * gridDim.y;
  int swz = (lin & 7) * (nwg >> 3) + (lin >> 3);
  int bx = swz % gridDim.x, by = swz / gridDim.x;
  const int m0 = by * 256, n0 = bx * 256;

  const size_t ld = (size_t)K * 2;
  const char* Ag = (const char*)A + (size_t)m0 * ld;
  const char* Bg = (const char*)BT + (size_t)n0 * ld;
  const int NT = K >> 6;
  const char* lsc = (const char*)ls;

  const int swz4 = (l15 & 7) << 4;
  const int bk0 = (l15 * 128 + lg * 16) ^ swz4;
  const int bk1 = (l15 * 128 + 64 + lg * 16) ^ swz4;
  const int vA_0 = bk0 + wm * 16384, vA_1 = bk1 + wm * 16384;
  const int vB_0 = bk0 + wn * 8192 + 65536, vB_1 = bk1 + wn * 8192 + 65536;

  const int srow = wid * 8 + (lane >> 3);
  const int kperm = ((lane & 7) ^ (lane >> 3)) << 4;
  const char* AgL = Ag + (size_t)srow * ld + kperm;
  const char* BgL = Bg + (size_t)srow * ld + kperm;

  f32x4 acc[8][4] = {};
  bf16x8 afr[4][2], bfr0[2][2], bfr1[2][2];

  // prologue: tile 0 -> A0,B0
  STG(AgL, 0, 0); STG(AgL, 0, 1);
  STG(BgL, 65536, 0); STG(BgL, 65536, 1);

  for (int u = 0; u < NT; u += 2) {
    int t1 = u + 1;
    int t2 = u + 2; if (t2 >= NT) t2 = 0;
    TILE(0, 0, 32768, 98304, t1);
    TILE(1, 1, 0, 65536, t2);
  }

  float bv[4];
#pragma unroll
  for (int nf = 0; nf < 4; ++nf) bv[nf] = bias[n0 + wn * 64 + nf * 16 + l15];
#pragma unroll
  for (int mf = 0; mf < 8; ++mf) {
    int rbase = m0 + wm * 128 + mf * 16 + lg * 4;
#pragma unroll
    for (int nf = 0; nf < 4; ++nf) {
      int col = n0 + wn * 64 + nf * 16 + l15;
#pragma unroll
      for (int j = 0; j < 4; ++j) {
        float v = acc[mf][nf][j] + bv[nf];
        if (ACT) v = v > 0.f ? v : 0.f;
        size_t idx = (size_t)(rbase + j) * N + col;
        if (OUTBF) ((unsigned short*)Cout)[idx] = bf16_rne(v);
        else       ((float*)Cout)[idx] = v;
      }
    }
  }
}

// ---------- GEMM2: 192x256 tile -> grid (2,128) = 256 blocks = 1/CU, 0% idle ----------
#define MFMA_T(AO, BO, MOFF, NOFF)                                                  \
  __builtin_amdgcn_s_setprio(1);                                                    \
  _Pragma("unroll") for (int i_ = 0; i_ < 3; ++i_)                                  \
  _Pragma("unroll") for (int j_ = 0; j_ < 2; ++j_)                                  \
  _Pragma("unroll") for (int ks_ = 0; ks_ < 2; ++ks_)                               \
    acc[(MOFF) + i_][(NOFF) + j_] = __builtin_amdgcn_mfma_f32_16x16x32_bf16(        \
        AO[i_][ks_], BO[j_][ks_], acc[(MOFF) + i_][(NOFF) + j_], 0, 0, 0);          \
  __builtin_amdgcn_s_setprio(0);

#define RA2(KS, ACH, MH, I) \
  (*(const bf16x8*)(lsc + ((ACH) * 24576 + (MH) * 6144 + (I) * 2048) + ((KS) ? vA_1 : vA_0)))
#define RB2(KS, BCH, JI) \
  (*(const bf16x8*)(lsc + ((BCH) * 32768 + (JI) * 2048) + ((KS) ? vB_1 : vB_0)))

#define STGA2(CHOFF, T)                                                           \
  {                                                                               \
    const char* p_ = AgL + (size_t)(T) * 128;                                     \
    gload16(p_,               (char*)ls + (CHOFF) + wid * 3072);                  \
    gload16(p_ + 8 * ld,      (char*)ls + (CHOFF) + wid * 3072 + 1024);           \
    gload16(p_ + 16 * ld,     (char*)ls + (CHOFF) + wid * 3072 + 2048);           \
  }
#define STGB2(CHOFF, T)                                                           \
  {                                                                               \
    const char* p_ = BgL + (size_t)(T) * 128;                                     \
    gload16(p_,               (char*)ls + (CHOFF) + wid * 4096);                  \
    gload16(p_ + 8 * ld,      (char*)ls + (CHOFF) + wid * 4096 + 1024);           \
    gload16(p_ + 16 * ld,     (char*)ls + (CHOFF) + wid * 4096 + 2048);           \
    gload16(p_ + 24 * ld,     (char*)ls + (CHOFF) + wid * 4096 + 3072);           \
  }

#define TILE2(ACH, BCH, ASO, BSO, T)                                              \
  {                                                                               \
    VMCNT0();                                                                     \
    BAR();                                                                        \
    _Pragma("unroll") for (int i = 0; i < 3; ++i) {                               \
      afl[i][0] = RA2(0, ACH, 0, i); afl[i][1] = RA2(1, ACH, 0, i);               \
    }                                                                             \
    _Pragma("unroll") for (int j = 0; j < 2; ++j) {                               \
      bfr0[j][0] = RB2(0, BCH, j); bfr0[j][1] = RB2(1, BCH, j);                   \
    }                                                                             \
    _Pragma("unroll") for (int j = 0; j < 2; ++j) {                               \
      bfr1[j][0] = RB2(0, BCH, 2 + j); bfr1[j][1] = RB2(1, BCH, 2 + j);           \
    }                                                                             \
    STGA2(ASO, T); STGB2(BSO, T);                                                 \
    LGKM4(); SB();                                                                \
    MFMA_T(afl, bfr0, 0, 0);                                                      \
    LGKM0(); SB();                                                                \
    MFMA_T(afl, bfr1, 0, 2);                                                      \
    _Pragma("unroll") for (int i = 0; i < 3; ++i) {                               \
      afl[i][0] = RA2(0, ACH, 1, i); afl[i][1] = RA2(1, ACH, 1, i);               \
    }                                                                             \
    LGKM0(); SB();                                                                \
    MFMA_T(afl, bfr1, 3, 2);                                                      \
    MFMA_T(afl, bfr0, 3, 0);                                                      \
  }

__global__ __launch_bounds__(512) void gemm192(const unsigned short* __restrict__ A,
                                               const unsigned short* __restrict__ BT,
                                               const float* __restrict__ bias,
                                               float* __restrict__ Cout) {
  __shared__ __attribute__((aligned(16))) short ls[57344];  // 112 KiB
  const int tid = threadIdx.x, lane = tid & 63, wid = tid >> 6;
  const int wm = wid >> 2, wn = wid & 3;
  const int l15 = lane & 15, lg = lane >> 4;

  int lin = blockIdx.y * gridDim.x + blockIdx.x;
  int nwg = gridDim.x * gridDim.y;
  int swz = (lin & 7) * (nwg >> 3) + (lin >> 3);
  int bx = swz % gridDim.x, by = swz / gridDim.x;
  const int m0 = by * 192, n0 = bx * 256;

  constexpr int K = 2048;
  const size_t ld = (size_t)K * 2;
  const char* Ag = (const char*)A + (size_t)m0 * ld;
  const char* Bg = (const char*)BT + (size_t)n0 * ld;
  constexpr int NT = K >> 6;  // 32
  const char* lsc = (const char*)ls;

  const int swz4 = (l15 & 7) << 4;
  const int bk0 = (l15 * 128 + lg * 16) ^ swz4;
  const int bk1 = (l15 * 128 + 64 + lg * 16) ^ swz4;
  const int vA_0 = bk0 + wm * 12288, vA_1 = bk1 + wm * 12288;
  const int vB_0 = bk0 + wn * 8192 + 49152, vB_1 = bk1 + wn * 8192 + 49152;

  const int kperm = ((lane & 7) ^ (lane >> 3)) << 4;
  const char* AgL = Ag + (size_t)(wid * 24 + (lane >> 3)) * ld + kperm;
  const char* BgL = Bg + (size_t)(wid * 32 + (lane >> 3)) * ld + kperm;

  f32x4 acc[6][4] = {};
  bf16x8 afl[3][2], bfr0[2][2], bfr1[2][2];

  STGA2(0, 0);
  STGB2(49152, 0);

  for (int u = 0; u < NT; u += 2) {
    int t1 = u + 1;
    int t2 = u + 2; if (t2 >= NT) t2 = 0;
    TILE2(0, 0, 24576, 81920, t1);
    TILE2(1, 1, 0, 49152, t2);
  }

  float bv[4];
#pragma unroll
  for (int nf = 0; nf < 4; ++nf) bv[nf] = bias[n0 + wn * 64 + nf * 16 + l15];
#pragma unroll
  for (int mf = 0; mf < 6; ++mf) {
    int rbase = m0 + wm * 96 + mf * 16 + lg * 4;
#pragma unroll
    for (int nf = 0; nf < 4; ++nf) {
      int col = n0 + wn * 64 + nf * 16 + l15;
#pragma unroll
      for (int j = 0; j < 4; ++j)
        Cout[(size_t)(rbase + j) * 512 + col] = acc[mf][nf][j] + bv[nf];
    }
  }
}

// ---------- per-task K = Es Es^T + eps*I, eta2 = log2(e)/(2*max row abs-sum) ----------
__global__ __launch_bounds__(256) void makeK(const float* __restrict__ E,
                                             float* __restrict__ Km,
                                             float* __restrict__ eta2v) {
  __shared__ float es[32][512];  // 64 KB
  const int b = blockIdx.x, tid = threadIdx.x;
  const float4* Eb = (const float4*)(E + (size_t)b * 32 * 512);
  float4* es4 = (float4*)&es[0][0];
  for (int i = tid; i < 32 * 128; i += 256) es4[i] = Eb[i];
  __syncthreads();

  const int s = tid >> 3, tq = tid & 7;
  const float4* rs4 = (const float4*)&es[s][0];
  const float4* rt0 = (const float4*)&es[tq * 4 + 0][0];
  const float4* rt1 = (const float4*)&es[tq * 4 + 1][0];
  const float4* rt2 = (const float4*)&es[tq * 4 + 2][0];
  const float4* rt3 = (const float4*)&es[tq * 4 + 3][0];
  float4 a0 = {0, 0, 0, 0}, a1 = {0, 0, 0, 0}, a2 = {0, 0, 0, 0}, a3 = {0, 0, 0, 0};
  for (int dd = 0; dd < 128; ++dd) {
    float4 av = rs4[dd];
    float4 b0 = rt0[dd], b1 = rt1[dd], b2 = rt2[dd], b3 = rt3[dd];
    a0.x = fmaf(av.x, b0.x, a0.x); a0.y = fmaf(av.y, b0.y, a0.y);
    a0.z = fmaf(av.z, b0.z, a0.z); a0.w = fmaf(av.w, b0.w, a0.w);
    a1.x = fmaf(av.x, b1.x, a1.x); a1.y = fmaf(av.y, b1.y, a1.y);
    a1.z = fmaf(av.z, b1.z, a1.z); a1.w = fmaf(av.w, b1.w, a1.w);
    a2.x = fmaf(av.x, b2.x, a2.x); a2.y = fmaf(av.y, b2.y, a2.y);
    a2.z = fmaf(av.z, b2.z, a2.z); a2.w = fmaf(av.w, b2.w, a2.w);
    a3.x = fmaf(av.x, b3.x, a3.x); a3.y = fmaf(av.y, b3.y, a3.y);
    a3.z = fmaf(av.z, b3.z, a3.z); a3.w = fmaf(av.w, b3.w, a3.w);
  }
  float kv[4] = { (a0.x + a0.y) + (a0.z + a0.w), (a1.x + a1.y) + (a1.z + a1.w),
                  (a2.x + a2.y) + (a2.z + a2.w), (a3.x + a3.y) + (a3.z + a3.w) };
  float p = 0.f;
#pragma unroll
  for (int j = 0; j < 4; j++) {
    if (s == tq * 4 + j) kv[j] += 1e-6f;
    p += fabsf(kv[j]);
    Km[(size_t)b * 1024 + s * 32 + tq * 4 + j] = kv[j];
  }
  p += __shfl_xor(p, 1); p += __shfl_xor(p, 2); p += __shfl_xor(p, 4);
  __syncthreads();
  float* rs = &es[0][0];
  if (tq == 0) rs[s] = p;
  __syncthreads();
  if (tid < 32) {
    float m = rs[tid];
    m = fmaxf(m, __shfl_xor(m, 1));
    m = fmaxf(m, __shfl_xor(m, 2));
    m = fmaxf(m, __shfl_xor(m, 4));
    m = fmaxf(m, __shfl_xor(m, 8));
    m = fmaxf(m, __shfl_xor(m, 16));
    if (tid == 0) eta2v[b] = 1.4426950408889634f / (2.0f * m);
  }
}

// ---------- QP: 500 EG iterations, one wave per task (readlane + full DPP) ----------
__global__ __launch_bounds__(256) void qp_kernel(const float* __restrict__ Km,
                                                 const float* __restrict__ eta2v,
                                                 float* __restrict__ alp) {
  const int lane = threadIdx.x & 63, wid = threadIdx.x >> 6;
  const int b = blockIdx.x * 4 + wid;
  const int s = lane & 31;
  const float* Kb = Km + (size_t)b * 1024;
  float kr[32];
#pragma unroll
  for (int i = 0; i < 8; i++) {
    float4 v = ((const float4*)(Kb + s * 32))[i];
    kr[i * 4 + 0] = v.x; kr[i * 4 + 1] = v.y; kr[i * 4 + 2] = v.z; kr[i * 4 + 3] = v.w;
  }
  const float kd = Kb[s * 33];
  const float eta2 = eta2v[b];
  const float c2p = fmaf(eta2, kd, 1.0f);
  const float m4n = -4.0f * eta2;
  float w = 0.03125f;
  for (int it = 0; it < 500; ++it) {
    float c0 = 0.f, c1 = 0.f, c2 = 0.f, c3 = 0.f, c4 = 0.f, c5 = 0.f, c6 = 0.f, c7 = 0.f;
#pragma unroll
    for (int t = 0; t < 4; ++t) {
      c0 = fmaf(kr[t],      lane_f(w, t),      c0);
      c1 = fmaf(kr[4 + t],  lane_f(w, 4 + t),  c1);
      c2 = fmaf(kr[8 + t],  lane_f(w, 8 + t),  c2);
      c3 = fmaf(kr[12 + t], lane_f(w, 12 + t), c3);
      c4 = fmaf(kr[16 + t], lane_f(w, 16 + t), c4);
      c5 = fmaf(kr[20 + t], lane_f(w, 20 + t), c5);
      c6 = fmaf(kr[24 + t], lane_f(w, 24 + t), c6);
      c7 = fmaf(kr[28 + t], lane_f(w, 28 + t), c7);
    }
    float tK = (((c0 + c1) + (c2 + c3)) + ((c4 + c5) + (c6 + c7)));
    float r = w;
    r = dpp_add<0x128>(r);
    r = dpp_add<0x124>(r);
    r = dpp_add<0x122>(r);
    r = dpp_add<0x121>(r);
    r = dpp_add<0x142>(r);
    r = dpp_add<0x143>(r);
    float R2 = __builtin_amdgcn_rcpf(lane_f(r, 63));
    float z = fmaf(m4n * R2, tK, c2p);
    w = (w * R2) * __builtin_amdgcn_exp2f(z);
  }
  float r = w;
  r = dpp_add<0x128>(r);
  r = dpp_add<0x124>(r);
  r = dpp_add<0x122>(r);
  r = dpp_add<0x121>(r);
  r = dpp_add<0x142>(r);
  r = dpp_add<0x143>(r);
  float R2 = __builtin_amdgcn_rcpf(lane_f(r, 63));
  if (lane < 32) alp[(size_t)b * 32 + s] = 2.0f * w * R2;
}

// ---------- centers[b] = sum_s alpha[b][s] * Es[b][s][:] ----------
__global__ __launch_bounds__(128) void centers_k(const float* __restrict__ alp,
                                                 const float* __restrict__ E,
                                                 float* __restrict__ ctr) {
  const int b = blockIdx.x, t = threadIdx.x;
  __shared__ float av[32];
  if (t < 32) av[t] = alp[(size_t)b * 32 + t];
  __syncthreads();
  const float4* Eb = (const float4*)(E + (size_t)b * 32 * 512);
  float4 c = {0, 0, 0, 0};
#pragma unroll 8
  for (int sIdx = 0; sIdx < 32; sIdx++) {
    float a = av[sIdx];
    float4 v = Eb[sIdx * 128 + t];
    c.x = fmaf(a, v.x, c.x); c.y = fmaf(a, v.y, c.y);
    c.z = fmaf(a, v.z, c.z); c.w = fmaf(a, v.w, c.w);
  }
  ((float4*)ctr)[b * 128 + t] = c;
}

// ---------- logits[b][q] = -||center[b] - Eq[b][q]||^2 ----------
__global__ __launch_bounds__(256) void logits_k(const float* __restrict__ ctr,
                                                const float* __restrict__ E,
                                                float* __restrict__ out) {
  const int b = blockIdx.x, lane = threadIdx.x & 63, w = threadIdx.x >> 6;
  const float4* C4 = (const float4*)(ctr + (size_t)b * 512);
  const float4 cA = C4[lane * 2], cB = C4[lane * 2 + 1];
  const float4* Q4 = (const float4*)(E + (size_t)(8192 + b * 64) * 512);
  for (int q = w; q < 64; q += 4) {
    float4 e0 = Q4[(size_t)q * 128 + lane * 2];
    float4 e1 = Q4[(size_t)q * 128 + lane * 2 + 1];
    float d, ss = 0.f;
    d = cA.x - e0.x; ss = fmaf(d, d, ss);
    d = cA.y - e0.y; ss = fmaf(d, d, ss);
    d = cA.z - e0.z; ss = fmaf(d, d, ss);
    d = cA.w - e0.w; ss = fmaf(d, d, ss);
    d = cB.x - e1.x; ss = fmaf(d, d, ss);
    d = cB.y - e1.y; ss = fmaf(d, d, ss);
    d = cB.z - e1.z; ss = fmaf(d, d, ss);
    d = cB.w - e1.w; ss = fmaf(d, d, ss);
    ss += __shfl_xor(ss, 1);  ss += __shfl_xor(ss, 2);  ss += __shfl_xor(ss, 4);
    ss += __shfl_xor(ss, 8);  ss += __shfl_xor(ss, 16); ss += __shfl_xor(ss, 32);
    if (lane == 0) out[b * 64 + q] = -ss;
  }
}

// ---------- launch ----------
extern "C" void kernel_launch(void* const* d_in, const int* in_sizes, int n_in,
                              void* d_out, int out_size, void* d_ws, size_t ws_size,
                              hipStream_t stream) {
  const float* sup = (const float*)d_in[0];
  const float* qry = (const float*)d_in[1];
  const float* W1  = (const float*)d_in[2];
  const float* b1  = (const float*)d_in[3];
  const float* W2  = (const float*)d_in[4];
  const float* b2  = (const float*)d_in[5];
  float* out = (float*)d_out;

  char* ws = (char*)d_ws;
  unsigned short* H   = (unsigned short*)(ws);               // 24576*2048*2
  unsigned short* Xbf = (unsigned short*)(ws + 100663296);   // 24576*1024*2
  float* E    = (float*)(ws + 100663296);                    // aliases Xbf (dead after GEMM1)
  unsigned short* W1T = (unsigned short*)(ws + 150994944);
  unsigned short* W2T = (unsigned short*)(ws + 155189248);
  float* Km   = (float*)(ws + 157286400);
  float* eta2 = (float*)(ws + 158334976);
  float* alp  = (float*)(ws + 158336000);
  float* ctr  = (float*)(ws + 158368768);

  castx<<<dim3(2048), dim3(256), 0, stream>>>(sup, qry, Xbf);
  transcast<<<dim3(64, 32), dim3(256), 0, stream>>>(W1, W1T, 1024, 2048);
  transcast<<<dim3(16, 64), dim3(256), 0, stream>>>(W2, W2T, 2048, 512);
  gemm256<1, 1><<<dim3(8, 96), dim3(512), 0, stream>>>(Xbf, W1T, b1, (void*)H, 24576, 2048, 1024);
  gemm192<<<dim3(2, 128), dim3(512), 0, stream>>>(H, W2T, b2, E);
  makeK<<<dim3(256), dim3(256), 0, stream>>>(E, Km, eta2);
  qp_kernel<<<dim3(64), dim3(256), 0, stream>>>(Km, eta2, alp);
  centers_k<<<dim3(256), dim3(128), 0, stream>>>(alp, E, ctr);
  logits_k<<<dim3(256), dim3(256), 0, stream>>>(ctr, E, out);
}